// Round 5
// baseline (693.649 us; speedup 1.0000x reference)
//
#include <hip/hip_runtime.h>
#include <hip/hip_bf16.h>
#include <stdint.h>

#define DMODEL 1024
#define NEXP 32
#define ESZ 256
#define NTOK 8192
#define NH 4
#define NBK 128   // (expert, head) buckets, e-major j-minor

typedef __hip_bfloat16 bf16;
typedef short bf16x8 __attribute__((ext_vector_type(8)));
typedef float f32x4 __attribute__((ext_vector_type(4)));

__device__ __forceinline__ void pack8(const float4& a, const float4& b, bf16* t) {
    t[0] = __float2bfloat16(a.x); t[1] = __float2bfloat16(a.y);
    t[2] = __float2bfloat16(a.z); t[3] = __float2bfloat16(a.w);
    t[4] = __float2bfloat16(b.x); t[5] = __float2bfloat16(b.y);
    t[6] = __float2bfloat16(b.z); t[7] = __float2bfloat16(b.w);
}

// ---------------- selection (pure f32): logits -> top-4 -> gates (NO atomics) ----------------
__global__ void sel_kernel(const float* __restrict__ x, const float* __restrict__ esel,
                           int* __restrict__ eidx, float* __restrict__ egate) {
    int lane = threadIdx.x & 63;
    int wid = threadIdx.x >> 6;
    int t = blockIdx.x * 4 + wid;

    const float* xp = x + (size_t)t * DMODEL + lane * 16;
    float xv[16];
    *(float4*)&xv[0]  = *(const float4*)(xp);
    *(float4*)&xv[4]  = *(const float4*)(xp + 4);
    *(float4*)&xv[8]  = *(const float4*)(xp + 8);
    *(float4*)&xv[12] = *(const float4*)(xp + 12);

    __shared__ float sc[4][NEXP];
    for (int e = 0; e < NEXP; ++e) {
        const float* sp = esel + (size_t)e * DMODEL + lane * 16;
        float4 p0 = *(const float4*)(sp);
        float4 p1 = *(const float4*)(sp + 4);
        float4 p2 = *(const float4*)(sp + 8);
        float4 p3 = *(const float4*)(sp + 12);
        float s = xv[0]*p0.x + xv[1]*p0.y + xv[2]*p0.z + xv[3]*p0.w
                + xv[4]*p1.x + xv[5]*p1.y + xv[6]*p1.z + xv[7]*p1.w
                + xv[8]*p2.x + xv[9]*p2.y + xv[10]*p2.z + xv[11]*p2.w
                + xv[12]*p3.x + xv[13]*p3.y + xv[14]*p3.z + xv[15]*p3.w;
        #pragma unroll
        for (int o = 32; o > 0; o >>= 1) s += __shfl_xor(s, o, 64);
        if (lane == 0) sc[wid][e] = s;
    }

    if (lane == 0) {
        // strict > scan: lowest index wins ties (matches lax.top_k; sigmoid is monotone)
        for (int j = 0; j < NH; ++j) {
            float m = -1e30f; int mi = 0;
            for (int e = 0; e < NEXP; ++e) {
                float v = sc[wid][e];
                if (v > m) { m = v; mi = e; }
            }
            sc[wid][mi] = -1e30f;
            float g = 1.f / (1.f + expf(-m));   // sigmoid of logit
            eidx[t * NH + j] = mi;
            egate[t * NH + j] = g;
        }
    }
}

// ---------------- per-(expert,head) histogram: 128 buckets, contention-free ----------------
// head of entry i is (i & 3); within a 64-lane wave over a quarter, head == (lane & 3).
__global__ void hist4_kernel(const int* __restrict__ eidx, int* __restrict__ counts4,
                             int* __restrict__ counts4_q) {
    int k = blockIdx.x;            // 128 blocks: e = k>>2, j = k&3
    int e = k >> 2, j = k & 3;
    int w = threadIdx.x >> 6;      // wave = quarter of the 32768 entries
    int lane = threadIdx.x & 63;
    const int* p = eidx + w * 8192;
    int match_j = ((lane & 3) == j);
    int cnt = 0;
    for (int it = 0; it < 128; ++it)
        cnt += (p[it * 64 + lane] == e) & match_j;
    #pragma unroll
    for (int o = 32; o > 0; o >>= 1) cnt += __shfl_xor(cnt, o, 64);
    __shared__ int s_q[4];
    if (lane == 0) s_q[w] = cnt;
    __syncthreads();
    if (threadIdx.x == 0) {
        counts4[k] = s_q[0] + s_q[1] + s_q[2] + s_q[3];
        counts4_q[k * 4 + 0] = s_q[0];
        counts4_q[k * 4 + 1] = s_q[1];
        counts4_q[k * 4 + 2] = s_q[2];
        counts4_q[k * 4 + 3] = s_q[3];
    }
}

// ---------------- tiny exclusive scan over 128 bucket counts + per-expert aggregates ----------------
__global__ void scan4_kernel(const int* __restrict__ counts4, int* __restrict__ offsets4,
                             int* __restrict__ countsE, int* __restrict__ offsetsE) {
    if (threadIdx.x == 0) {
        int s = 0;
        for (int k = 0; k < NBK; ++k) {
            offsets4[k] = s;
            if ((k & 3) == 0) offsetsE[k >> 2] = s;   // expert range starts at its j=0 bucket
            s += counts4[k];
        }
        for (int e = 0; e < NEXP; ++e)
            countsE[e] = counts4[4*e] + counts4[4*e+1] + counts4[4*e+2] + counts4[4*e+3];
    }
}

// ---------------- deterministic ballot compaction into (e,head) buckets (NO atomics) ----------------
__global__ void compact4_kernel(const int* __restrict__ eidx, const float* __restrict__ egate,
                                const int* __restrict__ offsets4, const int* __restrict__ counts4_q,
                                int* __restrict__ btok, float* __restrict__ bgate) {
    int k = blockIdx.x;   // 128
    int q = blockIdx.y;   // 4
    int e = k >> 2, j = k & 3;
    int lane = threadIdx.x;  // block = 64 (one wave)
    int base = offsets4[k];
    #pragma unroll
    for (int kk = 0; kk < 4; ++kk) if (kk < q) base += counts4_q[k * 4 + kk];
    const int* p = eidx + q * 8192;
    const float* g = egate + q * 8192;
    bool me = (lane & 3) == j;     // head index within the wave's stride-64 window
    int v = p[lane];
    for (int it = 0; it < 128; ++it) {
        int v_next = (it < 127) ? p[(it + 1) * 64 + lane] : 0;   // prefetch
        unsigned long long m = __ballot(v == e && me);
        if (v == e && me) {
            int i = it * 64 + lane;
            int pos = base + __popcll(m & ((1ull << lane) - 1ull));
            btok[pos] = (q * 8192 + i) >> 2;      // token index
            bgate[pos] = g[i];
        }
        base += __popcll(m);
        v = v_next;
    }
}

// ---------------- per-expert transpose+convert: f32 in[e][R][C] -> bf16 out[e][C][R] ----------------
__global__ void transpose_conv_kernel(const float* __restrict__ in, bf16* __restrict__ out,
                                      int R, int C) {
    __shared__ bf16 tile[64][72];
    int e = blockIdx.z, tr = blockIdx.y, tc = blockIdx.x;
    const float* src = in + ((size_t)e * R + tr * 64) * C + tc * 64;
    #pragma unroll
    for (int i = 0; i < 2; ++i) {
        int c = threadIdx.x + 256 * i;
        int r = c >> 3, c8 = c & 7;
        float4 p0 = *(const float4*)(src + (size_t)r * C + c8 * 8);
        float4 p1 = *(const float4*)(src + (size_t)r * C + c8 * 8 + 4);
        bf16 t8[8];
        pack8(p0, p1, t8);
        *(uint4*)&tile[r][c8 * 8] = *(uint4*)t8;
    }
    __syncthreads();
    bf16* dst = out + ((size_t)e * C + tc * 64) * R + tr * 64;
    #pragma unroll
    for (int i = 0; i < 2; ++i) {
        int c = threadIdx.x + 256 * i;
        int oc = c >> 3, c8 = c & 7;
        bf16 tmp[8];
        #pragma unroll
        for (int j = 0; j < 8; ++j) tmp[j] = tile[c8 * 8 + j][oc];
        *(uint4*)(dst + (size_t)oc * R + c8 * 8) = *(uint4*)tmp;
    }
}

// ---------------- stage A kernel: Hg[entry][256] = bf16( gate * relu(Xg @ K_e) ) ----------------
// Processes an expert's FULL contiguous entry range (all 4 head sub-buckets).
__global__ __launch_bounds__(256) void moe_h_kernel(
    const float* __restrict__ x, const bf16* __restrict__ keysT,
    const int* __restrict__ countsE, const int* __restrict__ offsetsE,
    const int* __restrict__ btok, const float* __restrict__ bgate,
    bf16* __restrict__ Hg) {
    int e = blockIdx.y;
    int n = countsE[e];
    int tile = blockIdx.x;
    if (tile * 64 >= n) return;
    int off = offsetsE[e];
    int tid = threadIdx.x;
    int lane = tid & 63;
    int w = tid >> 6;

    // LDS: Xg[64][72] @0 (9216 B) + KT[256][72] @9216 (36864 B) = 46080 B
    //      epilogue overlays H[64][264] @0 (33792 B)
    __shared__ __align__(16) unsigned char smem[46080];
    bf16* Xg = (bf16*)smem;
    bf16* KT = (bf16*)(smem + 9216);
    bf16* H  = (bf16*)smem;
    __shared__ int s_tok[64];
    __shared__ float s_gate[64];

    if (tid < 64) {
        int idxr = tile * 64 + tid;
        bool valid = idxr < n;
        int tok = valid ? btok[off + idxr] : 0;
        s_tok[tid] = tok & (NTOK - 1);           // defensive mask
        float g = valid ? bgate[off + idxr] : 0.f;
        s_gate[tid] = (g == g) ? g : 0.f;        // defensive NaN scrub
    }
    __syncthreads();

    int lr = lane & 15;   // fragment row/col index
    int lg = lane >> 4;   // quad
    int c16 = tid & 7;
    int r0 = tid >> 3;    // 0..31

    f32x4 acc[16] = {};   // wave w: H rows [16w,16w+16) x cols [0,256)

    const bf16* kbase = keysT + (size_t)e * ESZ * DMODEL;
    const float* xrA = x + (size_t)s_tok[r0] * DMODEL;
    const float* xrB = x + (size_t)s_tok[r0 + 32] * DMODEL;

    for (int kb = 0; kb < 16; ++kb) {
        // stage Xg [64][64] with inline f32 -> bf16 conversion
        {
            float4 a0 = *(const float4*)(xrA + kb * 64 + c16 * 8);
            float4 a1 = *(const float4*)(xrA + kb * 64 + c16 * 8 + 4);
            bf16 t8[8];
            pack8(a0, a1, t8);
            *(uint4*)&Xg[r0 * 72 + c16 * 8] = *(uint4*)t8;
            float4 b0 = *(const float4*)(xrB + kb * 64 + c16 * 8);
            float4 b1 = *(const float4*)(xrB + kb * 64 + c16 * 8 + 4);
            pack8(b0, b1, t8);
            *(uint4*)&Xg[(r0 + 32) * 72 + c16 * 8] = *(uint4*)t8;
        }
        // stage KT [256][64] (keysT rows are contiguous in d, already bf16)
        #pragma unroll
        for (int i = 0; i < 8; ++i) {
            int h = r0 + 32 * i;
            *(uint4*)&KT[h * 72 + c16 * 8] =
                *(const uint4*)(kbase + (size_t)h * DMODEL + kb * 64 + c16 * 8);
        }
        __syncthreads();
        #pragma unroll
        for (int ks = 0; ks < 2; ++ks) {
            bf16x8 a = *(bf16x8*)&Xg[(w * 16 + lr) * 72 + ks * 32 + lg * 8];
            #pragma unroll
            for (int ct = 0; ct < 16; ++ct) {
                bf16x8 b = *(bf16x8*)&KT[(ct * 16 + lr) * 72 + ks * 32 + lg * 8];
                acc[ct] = __builtin_amdgcn_mfma_f32_16x16x32_bf16(a, b, acc[ct], 0, 0, 0);
            }
        }
        __syncthreads();
    }

    // relu + gate, f32 -> bf16 into H (LDS), then coalesced copy-out to Hg
    int rbase = w * 16 + lg * 4;
    {
        float g0 = s_gate[rbase + 0], g1 = s_gate[rbase + 1];
        float g2 = s_gate[rbase + 2], g3 = s_gate[rbase + 3];
        #pragma unroll
        for (int ct = 0; ct < 16; ++ct) {
            int col = ct * 16 + lr;
            H[(rbase + 0) * 264 + col] = __float2bfloat16(fmaxf(acc[ct][0], 0.f) * g0);
            H[(rbase + 1) * 264 + col] = __float2bfloat16(fmaxf(acc[ct][1], 0.f) * g1);
            H[(rbase + 2) * 264 + col] = __float2bfloat16(fmaxf(acc[ct][2], 0.f) * g2);
            H[(rbase + 3) * 264 + col] = __float2bfloat16(fmaxf(acc[ct][3], 0.f) * g3);
        }
    }
    __syncthreads();

    // copy H[64][256] -> Hg[off + tile*64 + r][256], guarded at row granularity
    #pragma unroll
    for (int i = 0; i < 2; ++i) {
        int r = r0 + 32 * i;
        if (tile * 64 + r < n) {
            bf16* dst = Hg + (size_t)(off + tile * 64 + r) * ESZ;
            #pragma unroll
            for (int c = 0; c < 4; ++c)
                *(uint4*)(dst + c * 64 + c16 * 8) = *(uint4*)&H[r * 264 + c * 64 + c16 * 8];
        }
    }
}

// ---------------- stage B kernel (per head rank): out[tok] {=, +=} Hg[entry] @ V_e ----------------
// One launch per head j (stream-serialized). Within a launch every token appears EXACTLY ONCE
// -> plain f32 store (j==0) / read-modify-write (j>0). NO atomics, no out memset.
// Grid-stride tile loop makes any bucket-size skew safe with a small grid.
__global__ __launch_bounds__(256) void moe_y_kernel(
    const bf16* __restrict__ Hg, const bf16* __restrict__ valuesT,
    const int* __restrict__ counts4, const int* __restrict__ offsets4,
    const int* __restrict__ btok, float* __restrict__ out, int head) {
    int e = blockIdx.z;
    int k = e * 4 + head;
    int n = counts4[k];
    int off = offsets4[k];
    int vcb = blockIdx.y * 256;        // v-chunk base
    int tid = threadIdx.x;
    int lane = tid & 63;
    int w = tid >> 6;
    int lr = lane & 15;
    int lg = lane >> 4;
    int c16 = tid & 7;
    int r0 = tid >> 3;    // 0..31

    // LDS: Hs[64][72] @0 (9216 B) + VTs[256][72] @9216 (36864 B) = 46080 B
    __shared__ __align__(16) unsigned char smem[46080];
    bf16* Hs  = (bf16*)smem;
    bf16* VTs = (bf16*)(smem + 9216);
    __shared__ int s_tok[64];

    const bf16* vbase = valuesT + (size_t)e * DMODEL * ESZ + (size_t)vcb * ESZ;

    for (int tile = blockIdx.x; tile * 64 < n; tile += gridDim.x) {
        if (tid < 64) {
            int idxr = tile * 64 + tid;
            int tok = (idxr < n) ? btok[off + idxr] : 0;
            s_tok[tid] = tok & (NTOK - 1);
        }
        __syncthreads();

        // clamp tail-row entry indices so staging reads stay inside Hg (data unused: store guarded)
        int hA = off + tile * 64 + r0;      if (hA > NTOK * NH - 1) hA = NTOK * NH - 1;
        int hB = off + tile * 64 + r0 + 32; if (hB > NTOK * NH - 1) hB = NTOK * NH - 1;
        const bf16* hrA = Hg + (size_t)hA * ESZ;
        const bf16* hrB = Hg + (size_t)hB * ESZ;

        f32x4 acc[16] = {};   // wave w: rows [16w,16w+16) x v-cols [0,256) of this chunk

        for (int kb = 0; kb < 4; ++kb) {
            // stage Hs [64][64] — entry-contiguous rows, straight 16B copies
            *(uint4*)&Hs[r0 * 72 + c16 * 8] = *(const uint4*)(hrA + kb * 64 + c16 * 8);
            *(uint4*)&Hs[(r0 + 32) * 72 + c16 * 8] = *(const uint4*)(hrB + kb * 64 + c16 * 8);
            // stage VTs [256 v][64 h] (valuesT rows contiguous in h)
            #pragma unroll
            for (int i = 0; i < 8; ++i) {
                int vr = r0 + 32 * i;
                *(uint4*)&VTs[vr * 72 + c16 * 8] =
                    *(const uint4*)(vbase + (size_t)vr * ESZ + kb * 64 + c16 * 8);
            }
            __syncthreads();
            #pragma unroll
            for (int ks = 0; ks < 2; ++ks) {
                bf16x8 a = *(bf16x8*)&Hs[(w * 16 + lr) * 72 + ks * 32 + lg * 8];
                #pragma unroll
                for (int ct = 0; ct < 16; ++ct) {
                    bf16x8 b = *(bf16x8*)&VTs[(ct * 16 + lr) * 72 + ks * 32 + lg * 8];
                    acc[ct] = __builtin_amdgcn_mfma_f32_16x16x32_bf16(a, b, acc[ct], 0, 0, 0);
                }
            }
            __syncthreads();
        }

        // epilogue: non-atomic store (head 0) or read-modify-write (heads 1..3)
        int rbase = w * 16 + lg * 4;
        if (head == 0) {
            #pragma unroll
            for (int ct = 0; ct < 16; ++ct) {
                int v = vcb + ct * 16 + lr;
                #pragma unroll
                for (int r = 0; r < 4; ++r) {
                    int row = rbase + r;
                    if (tile * 64 + row < n)
                        out[(size_t)s_tok[row] * DMODEL + v] = acc[ct][r];
                }
            }
        } else {
            #pragma unroll
            for (int ct = 0; ct < 16; ++ct) {
                int v = vcb + ct * 16 + lr;
                #pragma unroll
                for (int r = 0; r < 4; ++r) {
                    int row = rbase + r;
                    if (tile * 64 + row < n) {
                        float* p = &out[(size_t)s_tok[row] * DMODEL + v];
                        *p += acc[ct][r];
                    }
                }
            }
        }
        __syncthreads();   // all lanes done with s_tok before next tile overwrites it
    }
}

extern "C" void kernel_launch(void* const* d_in, const int* in_sizes, int n_in,
                              void* d_out, int out_size, void* d_ws, size_t ws_size,
                              hipStream_t stream) {
    const float* x      = (const float*)d_in[0];
    const float* keys   = (const float*)d_in[1];
    const float* values = (const float*)d_in[2];
    const float* esel   = (const float*)d_in[3];
    float* out = (float*)d_out;   // [8192][1024] f32 = 32 MiB; head-0 pass writes every element

    // Workspace map — total exactly 51380224 B (proven-safe bound):
    uint8_t* ws = (uint8_t*)d_ws;
    int*   eidx      = (int*)(ws);                        // [8192][4]   131072 B
    float* egate     = (float*)(ws + 131072);             // [8192][4]   131072 B
    int*   btok      = (int*)(ws + 262144);               // [32768]     131072 B
    float* bgate     = (float*)(ws + 393216);             // [32768]     131072 B
    int*   counts4   = (int*)(ws + 524288);               // [128]       512 B
    int*   offsets4  = (int*)(ws + 524800);               // [128]       512 B
    int*   counts4_q = (int*)(ws + 525312);               // [128][4]    2048 B
    int*   countsE   = (int*)(ws + 527360);               // [32]        128 B
    int*   offsetsE  = (int*)(ws + 527488);               // [32]        128 B
    bf16*  keysT     = (bf16*)(ws + 1048576);             // 16 MiB: [32][256 h][1024 d]
    bf16*  valuesT   = (bf16*)(ws + 17825792);            // 16 MiB: [32][1024 v][256 h]
    bf16*  Hg        = (bf16*)(ws + 34603008);            // 16 MiB: [32768 entries][256 h] (ends 51380224)

    transpose_conv_kernel<<<dim3(16, 4, 32), 256, 0, stream>>>(values, valuesT, ESZ, DMODEL);
    transpose_conv_kernel<<<dim3(4, 16, 32), 256, 0, stream>>>(keys, keysT, DMODEL, ESZ);
    sel_kernel<<<NTOK / 4, 256, 0, stream>>>(x, esel, eidx, egate);
    hist4_kernel<<<NBK, 256, 0, stream>>>(eidx, counts4, counts4_q);
    scan4_kernel<<<1, 64, 0, stream>>>(counts4, offsets4, countsE, offsetsE);
    compact4_kernel<<<dim3(NBK, 4), 64, 0, stream>>>(eidx, egate, offsets4, counts4_q, btok, bgate);
    moe_h_kernel<<<dim3(128, NEXP), 256, 0, stream>>>(x, keysT, countsE, offsetsE,
                                                      btok, bgate, Hg);
    // 4 stream-serialized head passes: head 0 stores, heads 1..3 accumulate (no atomics)
    for (int j = 0; j < NH; ++j)
        moe_y_kernel<<<dim3(16, 4, NEXP), 256, 0, stream>>>(Hg, valuesT, counts4, offsets4,
                                                            btok, out, j);
}

// Round 6
// 456.349 us; speedup vs baseline: 1.5200x; 1.5200x over previous
//
#include <hip/hip_runtime.h>
#include <hip/hip_bf16.h>
#include <stdint.h>

#define DMODEL 1024
#define NEXP 32
#define ESZ 256
#define NTOK 8192
#define NH 4

typedef __hip_bfloat16 bf16;
typedef short bf16x8 __attribute__((ext_vector_type(8)));
typedef float f32x4 __attribute__((ext_vector_type(4)));

__device__ __forceinline__ void pack8(const float4& a, const float4& b, bf16* t) {
    t[0] = __float2bfloat16(a.x); t[1] = __float2bfloat16(a.y);
    t[2] = __float2bfloat16(a.z); t[3] = __float2bfloat16(a.w);
    t[4] = __float2bfloat16(b.x); t[5] = __float2bfloat16(b.y);
    t[6] = __float2bfloat16(b.z); t[7] = __float2bfloat16(b.w);
}

// ---------------- selection + fused per-(expert,quarter) histogram ----------------
// f32 logits (selection must match reference top-k exactly); histogram via per-block
// LDS aggregation + at most 32 global atomics per block (contention trivial).
__global__ void sel_kernel(const float* __restrict__ x, const float* __restrict__ esel,
                           int* __restrict__ eidx, float* __restrict__ egate,
                           int* __restrict__ counts_q) {
    int lane = threadIdx.x & 63;
    int wid = threadIdx.x >> 6;
    int t = blockIdx.x * 4 + wid;

    const float* xp = x + (size_t)t * DMODEL + lane * 16;
    float xv[16];
    *(float4*)&xv[0]  = *(const float4*)(xp);
    *(float4*)&xv[4]  = *(const float4*)(xp + 4);
    *(float4*)&xv[8]  = *(const float4*)(xp + 8);
    *(float4*)&xv[12] = *(const float4*)(xp + 12);

    __shared__ float sc[4][NEXP];
    __shared__ int s_sel[4][NH];
    for (int e = 0; e < NEXP; ++e) {
        const float* sp = esel + (size_t)e * DMODEL + lane * 16;
        float4 p0 = *(const float4*)(sp);
        float4 p1 = *(const float4*)(sp + 4);
        float4 p2 = *(const float4*)(sp + 8);
        float4 p3 = *(const float4*)(sp + 12);
        float s = xv[0]*p0.x + xv[1]*p0.y + xv[2]*p0.z + xv[3]*p0.w
                + xv[4]*p1.x + xv[5]*p1.y + xv[6]*p1.z + xv[7]*p1.w
                + xv[8]*p2.x + xv[9]*p2.y + xv[10]*p2.z + xv[11]*p2.w
                + xv[12]*p3.x + xv[13]*p3.y + xv[14]*p3.z + xv[15]*p3.w;
        #pragma unroll
        for (int o = 32; o > 0; o >>= 1) s += __shfl_xor(s, o, 64);
        if (lane == 0) sc[wid][e] = s;
    }

    if (lane == 0) {
        // strict > scan: lowest index wins ties (matches lax.top_k; sigmoid is monotone)
        for (int j = 0; j < NH; ++j) {
            float m = -1e30f; int mi = 0;
            for (int e = 0; e < NEXP; ++e) {
                float v = sc[wid][e];
                if (v > m) { m = v; mi = e; }
            }
            sc[wid][mi] = -1e30f;
            float g = 1.f / (1.f + expf(-m));   // sigmoid of logit
            eidx[t * NH + j] = mi;
            egate[t * NH + j] = g;
            s_sel[wid][j] = mi;
        }
    }
    __syncthreads();

    // fused histogram: this block's 16 entries, all in quarter q = blockIdx.x>>9
    if (threadIdx.x < NEXP) {
        int cnt = 0;
        #pragma unroll
        for (int w2 = 0; w2 < 4; ++w2)
            #pragma unroll
            for (int j = 0; j < NH; ++j)
                cnt += (s_sel[w2][j] == (int)threadIdx.x);
        if (cnt) atomicAdd(&counts_q[threadIdx.x * 4 + (blockIdx.x >> 9)], cnt);
    }
}

// ---------------- 1-wave shuffle scan: counts_q -> counts, offsets ----------------
__global__ void scan_kernel(const int* __restrict__ counts_q, int* __restrict__ counts,
                            int* __restrict__ offsets) {
    int lane = threadIdx.x;   // block = 64 (one wave)
    int c = 0;
    if (lane < NEXP)
        c = counts_q[lane * 4] + counts_q[lane * 4 + 1]
          + counts_q[lane * 4 + 2] + counts_q[lane * 4 + 3];
    int v = c;
    #pragma unroll
    for (int o = 1; o < 64; o <<= 1) {
        int u = __shfl_up(v, o, 64);
        if (lane >= o) v += u;
    }
    if (lane < NEXP) { counts[lane] = c; offsets[lane] = v - c; }
}

// ---------------- deterministic ballot compaction into buckets (NO atomics) ----------------
__global__ void compact_kernel(const int* __restrict__ eidx, const float* __restrict__ egate,
                               const int* __restrict__ offsets, const int* __restrict__ counts_q,
                               int* __restrict__ btok, float* __restrict__ bgate) {
    int e = blockIdx.x;   // 32
    int q = blockIdx.y;   // 4
    int lane = threadIdx.x;  // block = 64 (one wave)
    int base = offsets[e];
    #pragma unroll
    for (int k = 0; k < 4; ++k) if (k < q) base += counts_q[e * 4 + k];
    const int* p = eidx + q * 8192;
    const float* g = egate + q * 8192;
    int v = p[lane];
    for (int it = 0; it < 128; ++it) {
        int v_next = (it < 127) ? p[(it + 1) * 64 + lane] : 0;   // prefetch
        unsigned long long m = __ballot(v == e);
        if (v == e) {
            int i = it * 64 + lane;
            int pos = base + __popcll(m & ((1ull << lane) - 1ull));
            btok[pos] = (q * 8192 + i) >> 2;      // token index
            bgate[pos] = g[i];
        }
        base += __popcll(m);
        v = v_next;
    }
}

// ---------------- per-expert transpose+convert: f32 in[e][R][C] -> bf16 out[e][C][R] ----------------
__global__ void transpose_conv_kernel(const float* __restrict__ in, bf16* __restrict__ out,
                                      int R, int C) {
    __shared__ bf16 tile[64][72];
    int e = blockIdx.z, tr = blockIdx.y, tc = blockIdx.x;
    const float* src = in + ((size_t)e * R + tr * 64) * C + tc * 64;
    #pragma unroll
    for (int i = 0; i < 2; ++i) {
        int c = threadIdx.x + 256 * i;
        int r = c >> 3, c8 = c & 7;
        float4 p0 = *(const float4*)(src + (size_t)r * C + c8 * 8);
        float4 p1 = *(const float4*)(src + (size_t)r * C + c8 * 8 + 4);
        bf16 t8[8];
        pack8(p0, p1, t8);
        *(uint4*)&tile[r][c8 * 8] = *(uint4*)t8;
    }
    __syncthreads();
    bf16* dst = out + ((size_t)e * C + tc * 64) * R + tr * 64;
    #pragma unroll
    for (int i = 0; i < 2; ++i) {
        int c = threadIdx.x + 256 * i;
        int oc = c >> 3, c8 = c & 7;
        bf16 tmp[8];
        #pragma unroll
        for (int j = 0; j < 8; ++j) tmp[j] = tile[c8 * 8 + j][oc];
        *(uint4*)(dst + (size_t)oc * R + c8 * 8) = *(uint4*)tmp;
    }
}

// ---------------- grouped expert GEMM v6: 8 waves (512 threads), fused A+B ----------------
// Same proven v3 math/sync structure, re-mapped to 8 waves for 2x resident waves/CU:
//   wave w -> (wr = w&3 row-quarter, wc = w>>2 col-half), acc[8] per wave (half of v3).
// Per-thread staging halves; barrier count 97 -> 66. LDS 71 KB -> 2 blocks/CU (16 waves/CU).
__global__ __launch_bounds__(512) void moe_gemm_kernel(
    const float* __restrict__ x, const bf16* __restrict__ keysT, const bf16* __restrict__ valuesT,
    const int* __restrict__ counts, const int* __restrict__ offsets,
    const int* __restrict__ btok, const float* __restrict__ bgate,
    float* __restrict__ out) {
    int e = blockIdx.y;
    int n = counts[e];
    int tile = blockIdx.x;
    if (tile * 64 >= n) return;
    int off = offsets[e];
    int tid = threadIdx.x;          // 0..511
    int lane = tid & 63;
    int w = tid >> 6;               // 0..7
    int wr = w & 3;                 // row-quarter (16 tokens)
    int wc = w >> 2;                // col-half (128 cols)
    int lr = lane & 15;
    int lg = lane >> 4;
    int c16 = tid & 7;
    int r0 = tid >> 3;              // 0..63 (one staging row per thread)

    // LDS: stage A Xg[64][72] @0 (9216) + KT[256][72] @9216 (36864) = 46080
    //      stage B H[64][264] @0 (33792) + VT[256][72] @33792 (36864) = 70656
    __shared__ __align__(16) unsigned char smem[70656];
    bf16* Xg = (bf16*)smem;
    bf16* KT = (bf16*)(smem + 9216);
    bf16* H  = (bf16*)smem;
    bf16* VT = (bf16*)(smem + 33792);
    __shared__ int s_tok[64];
    __shared__ float s_gate[64];

    if (tid < 64) {
        int idxr = tile * 64 + tid;
        bool valid = idxr < n;
        int tok = valid ? btok[off + idxr] : 0;
        s_tok[tid] = tok & (NTOK - 1);           // defensive mask
        float g = valid ? bgate[off + idxr] : 0.f;
        s_gate[tid] = (g == g) ? g : 0.f;        // defensive NaN scrub
    }
    __syncthreads();

    // =================== stage A: H = relu(X @ K_e) * gate ===================
    f32x4 acc[8] = {};
    const bf16* kbase = keysT + (size_t)e * ESZ * DMODEL;
    const float* xr = x + (size_t)s_tok[r0] * DMODEL;

    for (int kb = 0; kb < 16; ++kb) {
        // stage Xg [64][64]: one gathered row per thread, inline f32->bf16
        {
            float4 a0 = *(const float4*)(xr + kb * 64 + c16 * 8);
            float4 a1 = *(const float4*)(xr + kb * 64 + c16 * 8 + 4);
            bf16 t8[8];
            pack8(a0, a1, t8);
            *(uint4*)&Xg[r0 * 72 + c16 * 8] = *(uint4*)t8;
        }
        // stage KT [256][64]: 4 rows per thread (already bf16, contiguous in d)
        #pragma unroll
        for (int i = 0; i < 4; ++i) {
            int h = r0 + 64 * i;
            *(uint4*)&KT[h * 72 + c16 * 8] =
                *(const uint4*)(kbase + (size_t)h * DMODEL + kb * 64 + c16 * 8);
        }
        __syncthreads();
        #pragma unroll
        for (int ks = 0; ks < 2; ++ks) {
            bf16x8 a = *(bf16x8*)&Xg[(wr * 16 + lr) * 72 + ks * 32 + lg * 8];
            #pragma unroll
            for (int ct = 0; ct < 8; ++ct) {
                bf16x8 b = *(bf16x8*)&KT[(wc * 128 + ct * 16 + lr) * 72 + ks * 32 + lg * 8];
                acc[ct] = __builtin_amdgcn_mfma_f32_16x16x32_bf16(a, b, acc[ct], 0, 0, 0);
            }
        }
        __syncthreads();
    }

    // relu + gate, f32 -> bf16 into H[64][264] (each wave writes its quarter-rows x col-half)
    int rbase = wr * 16 + lg * 4;
    {
        float g0 = s_gate[rbase + 0], g1 = s_gate[rbase + 1];
        float g2 = s_gate[rbase + 2], g3 = s_gate[rbase + 3];
        #pragma unroll
        for (int ct = 0; ct < 8; ++ct) {
            int col = wc * 128 + ct * 16 + lr;
            H[(rbase + 0) * 264 + col] = __float2bfloat16(fmaxf(acc[ct][0], 0.f) * g0);
            H[(rbase + 1) * 264 + col] = __float2bfloat16(fmaxf(acc[ct][1], 0.f) * g1);
            H[(rbase + 2) * 264 + col] = __float2bfloat16(fmaxf(acc[ct][2], 0.f) * g2);
            H[(rbase + 3) * 264 + col] = __float2bfloat16(fmaxf(acc[ct][3], 0.f) * g3);
        }
    }
    __syncthreads();

    // =================== stage B: Y = H @ V_e -> atomic out ===================
    const bf16* vbase = valuesT + (size_t)e * DMODEL * ESZ;
    for (int vc = 0; vc < 4; ++vc) {          // 4 v-chunks of 256
        f32x4 yr[8] = {};
        #pragma unroll
        for (int hc = 0; hc < 4; ++hc) {      // K = 256 in 4 steps
            // stage VT [256 v][64 h]: 4 rows per thread
            #pragma unroll
            for (int i = 0; i < 4; ++i) {
                int vr = r0 + 64 * i;
                *(uint4*)&VT[vr * 72 + c16 * 8] =
                    *(const uint4*)(vbase + (size_t)(vc * 256 + vr) * ESZ + hc * 64 + c16 * 8);
            }
            __syncthreads();
            #pragma unroll
            for (int ks = 0; ks < 2; ++ks) {
                bf16x8 a = *(bf16x8*)&H[(wr * 16 + lr) * 264 + hc * 64 + ks * 32 + lg * 8];
                #pragma unroll
                for (int ct = 0; ct < 8; ++ct) {
                    bf16x8 b = *(bf16x8*)&VT[(wc * 128 + ct * 16 + lr) * 72 + ks * 32 + lg * 8];
                    yr[ct] = __builtin_amdgcn_mfma_f32_16x16x32_bf16(a, b, yr[ct], 0, 0, 0);
                }
            }
            __syncthreads();
        }
        // scatter-accumulate into out (memset'd at launch); tail rows guarded
        #pragma unroll
        for (int ct = 0; ct < 8; ++ct) {
            int v = vc * 256 + wc * 128 + ct * 16 + lr;
            #pragma unroll
            for (int r = 0; r < 4; ++r) {
                int row = rbase + r;
                if (tile * 64 + row < n) {
                    unsafeAtomicAdd(&out[(size_t)s_tok[row] * DMODEL + v], yr[ct][r]);
                }
            }
        }
    }
}

extern "C" void kernel_launch(void* const* d_in, const int* in_sizes, int n_in,
                              void* d_out, int out_size, void* d_ws, size_t ws_size,
                              hipStream_t stream) {
    const float* x      = (const float*)d_in[0];
    const float* keys   = (const float*)d_in[1];
    const float* values = (const float*)d_in[2];
    const float* esel   = (const float*)d_in[3];
    float* out = (float*)d_out;   // [8192][1024] f32 = 32 MiB, accumulated into directly

    // Workspace map — total within 51380224 B (proven-safe bound):
    uint8_t* ws = (uint8_t*)d_ws;
    int*   eidx     = (int*)(ws);                        // [8192][4]   131072 B
    float* egate    = (float*)(ws + 131072);             // [8192][4]   131072 B
    int*   btok     = (int*)(ws + 262144);               // [32768]     131072 B
    float* bgate    = (float*)(ws + 393216);             // [32768]     131072 B
    int*   counts   = (int*)(ws + 524288);               // [32]
    int*   offsets  = (int*)(ws + 524416);               // [32]
    int*   counts_q = (int*)(ws + 524544);               // [32][4]     512 B
    bf16*  keysT    = (bf16*)(ws + 1048576);             // 16 MiB: [32][256 h][1024 d]
    bf16*  valuesT  = (bf16*)(ws + 17825792);            // 16 MiB: [32][1024 v][256 h]

    hipMemsetAsync(out, 0, (size_t)NTOK * DMODEL * sizeof(float), stream);
    hipMemsetAsync(counts_q, 0, NEXP * 4 * sizeof(int), stream);

    transpose_conv_kernel<<<dim3(16, 4, 32), 256, 0, stream>>>(values, valuesT, ESZ, DMODEL);
    transpose_conv_kernel<<<dim3(4, 16, 32), 256, 0, stream>>>(keys, keysT, DMODEL, ESZ);
    sel_kernel<<<NTOK / 4, 256, 0, stream>>>(x, esel, eidx, egate, counts_q);
    scan_kernel<<<1, 64, 0, stream>>>(counts_q, counts, offsets);
    compact_kernel<<<dim3(NEXP, 4), 64, 0, stream>>>(eidx, egate, offsets, counts_q, btok, bgate);
    moe_gemm_kernel<<<dim3(128, NEXP), 512, 0, stream>>>(x, keysT, valuesT, counts, offsets,
                                                         btok, bgate, out);
}